// Round 13
// baseline (122.049 us; speedup 1.0000x reference)
//
#include <hip/hip_runtime.h>
#include <math.h>

#define NTOK 2048
#define DDIM 768
#define IDIM 384
#define NEXP 16
#define ECAP 2048                      // per-expert perm capacity
#define HSHARED (NEXP * ECAP)          // h row offset of shared-expert rows
#define GBLK (NTOK / 4)                // gate blocks = 512

// M=64 tiling
#define MT 64
#define NSHT2 32                       // shared m-tiles (2048/64)
#define NRT2 80                        // max routed m-tiles
#define NW2 ((NSHT2 + NRT2) * 6)       // 672 = 8 * 84
#define CH2 (NW2 / 8)                  // 84

// convroute grid segmentation: [0] route | zero 384 | x 192 | w1 816 | wd 816
#define CR_Z0 1
#define CR_X0 (CR_Z0 + 384)            // 385
#define CR_W10 (CR_X0 + 192)           // 577
#define CR_WD0 (CR_W10 + 816)          // 1393
#define CR_END (CR_WD0 + 816)          // 2209

typedef __attribute__((ext_vector_type(8))) short short8;   // 8 bf16 = 4 VGPR
typedef __attribute__((ext_vector_type(4))) float f32x4;    // MFMA C/D

__device__ __forceinline__ unsigned short f2bf(float f) {
    unsigned int u = __float_as_uint(f);
    unsigned int r = (u + 0x7fffu + ((u >> 16) & 1u)) >> 16;   // RNE
    return (unsigned short)r;
}

// ---------------- workspace layout (bytes) ----------------
// 0      counts[16]
// 1024   perm_t[16*2048] int   | 132096 perm_w[16*2048] f32
// 263168 p_partial[512*16] f32 | 295936 topk_i | 312320 topk_w
#define WS_XB   1048576u
#define WS_W1F  4194304u
#define WS_WDF  24248320u
#define WS_H    34275328u

// Standalone gate (own regalloc): shuffle-only softmax/top2. Wave = 1 token.
__global__ __launch_bounds__(256) void gate_kernel(
    const float* __restrict__ x, const float* __restrict__ gate_w,
    int* __restrict__ topk_i, float* __restrict__ topk_w,
    float* __restrict__ p_partial) {
    __shared__ float p_blk[16];
    int tid = threadIdx.x;
    if (tid < 16) p_blk[tid] = 0.f;
    __syncthreads();

    int wave = tid >> 6, lane = tid & 63;
    int n = blockIdx.x * 4 + wave;
    int e = lane >> 2, q = lane & 3;
    const float4* xr = (const float4*)(x + (size_t)n * DDIM);
    const float4* wr = (const float4*)(gate_w + (size_t)e * DDIM);
    float s = 0.f;
    #pragma unroll 4
    for (int k = q * 48; k < q * 48 + 48; ++k) {
        float4 a = xr[k], b = wr[k];
        s += a.x * b.x + a.y * b.y + a.z * b.z + a.w * b.w;
    }
    s += __shfl_xor(s, 1);
    s += __shfl_xor(s, 2);
    float logit = s * 2.5f;

    float m = logit;
    #pragma unroll
    for (int mask = 4; mask < 64; mask <<= 1)
        m = fmaxf(m, __shfl_xor(m, mask));
    float ex = __expf(logit - m);
    float sum = ex;
    #pragma unroll
    for (int mask = 4; mask < 64; mask <<= 1)
        sum += __shfl_xor(sum, mask);
    float sc = ex / sum;

    float v = sc; int idx = e;
    #pragma unroll
    for (int mask = 4; mask < 64; mask <<= 1) {
        float ov = __shfl_xor(v, mask);
        int   oi = __shfl_xor(idx, mask);
        if (ov > v || (ov == v && oi < idx)) { v = ov; idx = oi; }
    }
    float b0 = v; int i0 = idx;
    v = (e == i0) ? -1.f : sc; idx = e;
    #pragma unroll
    for (int mask = 4; mask < 64; mask <<= 1) {
        float ov = __shfl_xor(v, mask);
        int   oi = __shfl_xor(idx, mask);
        if (ov > v || (ov == v && oi < idx)) { v = ov; idx = oi; }
    }
    float b1 = v; int i1 = idx;
    float rs = 1.f / (b0 + b1);

    if (lane == 0) {
        topk_i[n * 2] = i0; topk_i[n * 2 + 1] = i1;
        topk_w[n * 2] = b0 * rs; topk_w[n * 2 + 1] = b1 * rs;
    }
    if (q == 0) atomicAdd(&p_blk[e], sc);   // LDS only
    __syncthreads();
    if (tid < 16) p_partial[blockIdx.x * 16 + tid] = p_blk[tid];
}

// Fused bulk: route(b0) | zero d_out | x conv | w1 conv (LDS transpose) |
// wd conv (LDS transpose). Reads AND writes coalesced.
__global__ __launch_bounds__(256) void convroute_kernel(
    const float* __restrict__ x,
    const float* __restrict__ rgw, const float* __restrict__ ruw,
    const float* __restrict__ sgw, const float* __restrict__ suw,
    const float* __restrict__ rdw, const float* __restrict__ sdw,
    float4* __restrict__ out4,
    unsigned short* __restrict__ xb, unsigned short* __restrict__ w1f,
    unsigned short* __restrict__ wdf,
    const int* __restrict__ topk_i, const float* __restrict__ topk_w,
    const float* __restrict__ p_partial,
    int* __restrict__ counts, int* __restrict__ perm_t, float* __restrict__ perm_w,
    float* __restrict__ out_aux) {
    __shared__ unsigned short sbuf[16 * 780];   // 24,960 B (max of all branches)
    int b = blockIdx.x, tid = threadIdx.x;

    if (b == 0) {                                    // ---- route ----
        float* s_p    = (float*)sbuf;                // 256
        float* s_psum = s_p + 256;                   // 16
        int*   s_cnt  = (int*)(s_psum + 16);         // 16
        int*   s_cur  = s_cnt + 16;                  // 16
        {
            int e = tid & 15, g = tid >> 4;
            float acc = 0.f;
            for (int bb = g; bb < GBLK; bb += 16) acc += p_partial[bb * 16 + e];
            s_p[tid] = acc;
        }
        if (tid < 16) { s_cnt[tid] = 0; s_cur[tid] = 0; }
        __syncthreads();
        if (tid < 16) {
            float a = 0.f;
            #pragma unroll
            for (int g = 0; g < 16; ++g) a += s_p[g * 16 + tid];
            s_psum[tid] = a;
        }
        for (int n = tid; n < NTOK; n += 256) {
            atomicAdd(&s_cnt[topk_i[n * 2]], 1);
            atomicAdd(&s_cnt[topk_i[n * 2 + 1]], 1);
        }
        __syncthreads();
        if (tid < 16) counts[tid] = s_cnt[tid];
        if (tid == 0) {
            float a = 0.f;
            for (int e = 0; e < 16; ++e) a += (float)s_cnt[e] * s_psum[e];
            out_aux[0] = a * 16.f / ((float)NTOK * (float)NTOK);
        }
        for (int n = tid; n < NTOK; n += 256) {
            #pragma unroll
            for (int k = 0; k < 2; ++k) {
                int e = topk_i[n * 2 + k];
                int pos = atomicAdd(&s_cur[e], 1);
                perm_t[e * ECAP + pos] = n;
                perm_w[e * ECAP + pos] = topk_w[n * 2 + k];
            }
        }
        return;
    }

    if (b < CR_X0) {                                 // ---- zero d_out ----
        float4 z = make_float4(0.f, 0.f, 0.f, 0.f);
        float4* dst = out4 + (b - CR_Z0) * 1024 + tid;
        #pragma unroll
        for (int j = 0; j < 4; ++j) dst[j * 256] = z;
        return;
    }

    if (b < CR_W10) {                                // ---- x conv (plain) ----
        int bb = b - CR_X0;
        #pragma unroll
        for (int j = 0; j < 4; ++j) {
            int i = bb * 1024 + j * 256 + tid;
            const float* s = x + (size_t)i * 8;
            float4 v0 = *(const float4*)s, v1 = *(const float4*)(s + 4);
            short8 o;
            o[0]=f2bf(v0.x); o[1]=f2bf(v0.y); o[2]=f2bf(v0.z); o[3]=f2bf(v0.w);
            o[4]=f2bf(v1.x); o[5]=f2bf(v1.y); o[6]=f2bf(v1.z); o[7]=f2bf(v1.w);
            *(short8*)(xb + (size_t)i * 8) = o;
        }
        return;
    }

    if (b < CR_WD0) {                                // ---- w1 conv, LDS transpose ----
        int bb = b - CR_W10;
        int E = bb / 48, rg = bb % 48;
        const float* gsrc_ = (E == 16) ? sgw : rgw + (size_t)E * (IDIM * DDIM);
        const float* usrc_ = (E == 16) ? suw : ruw + (size_t)E * (IDIM * DDIM);
        const float* src = ((rg & 1) ? usrc_ : gsrc_) + (size_t)(rg >> 1) * 16 * DDIM;
        #pragma unroll
        for (int i = 0; i < 12; ++i) {
            int idx = i * 256 + tid;                 // 0..3071 float4
            int r = idx / 192, c4 = idx - r * 192;
            float4 v = ((const float4*)(src + (size_t)r * DDIM))[c4];
            ushort4 o4;
            o4.x = f2bf(v.x); o4.y = f2bf(v.y); o4.z = f2bf(v.z); o4.w = f2bf(v.w);
            *(ushort4*)(sbuf + r * 780 + c4 * 4) = o4;
        }
        __syncthreads();
        unsigned short* wbase = w1f + (size_t)E * (DDIM * DDIM) + (size_t)rg * 24 * 512;
        #pragma unroll
        for (int c = 0; c < 6; ++c) {
            int cc = c * 256 + tid;                  // 0..1535 chunks
            int ks = cc >> 6, l = cc & 63;
            short8 v8 = *(const short8*)(sbuf + (l & 15) * 780 + ks * 32 + (l >> 4) * 8);
            *(short8*)(wbase + (size_t)(ks * 64 + l) * 8) = v8;
        }
        return;
    }

    {                                                // ---- wd conv, LDS transpose ----
        int bb = b - CR_WD0;
        int E = bb / 48, cg = bb % 48;
        const float* src = ((E == 16) ? sdw : rdw + (size_t)E * (DDIM * IDIM))
                         + (size_t)cg * 16 * IDIM;
        #pragma unroll
        for (int i = 0; i < 6; ++i) {
            int idx = i * 256 + tid;                 // 0..1535 float4
            int r = idx / 96, c4 = idx - r * 96;
            float4 v = ((const float4*)(src + (size_t)r * IDIM))[c4];
            ushort4 o4;
            o4.x = f2bf(v.x); o4.y = f2bf(v.y); o4.z = f2bf(v.z); o4.w = f2bf(v.w);
            *(ushort4*)(sbuf + r * 390 + c4 * 4) = o4;
        }
        __syncthreads();
        unsigned short* wbase = wdf + (size_t)E * (DDIM * IDIM) + (size_t)cg * 12 * 512;
        #pragma unroll
        for (int c = 0; c < 3; ++c) {
            int cc = c * 256 + tid;                  // 0..767 chunks
            int ks = cc >> 6, l = cc & 63;
            short8 v8 = *(const short8*)(sbuf + (l & 15) * 390 + ks * 32 + (l >> 4) * 8);
            *(short8*)(wbase + (size_t)(ks * 64 + l) * 8) = v8;
        }
    }
}

// XCD-bijective swizzle over the NW2 flattened (bx, y) space.
__device__ __forceinline__ void swz_decode(int lid, int& bx, int& y) {
    int wid = (lid & 7) * CH2 + (lid >> 3);
    bx = wid / 6;
    y = wid - bx * 6;
}

// routed tile index r -> (expert e, within-expert 64-tile t, count).
__device__ __forceinline__ bool tile_decode(const int* __restrict__ counts,
                                            int r, int& e, int& t, int& cnt) {
    int acc = 0;
    for (int ee = 0; ee < NEXP; ++ee) {
        int c = counts[ee];
        int tiles = (c + 63) >> 6;
        if (r < acc + tiles) { e = ee; t = r - acc; cnt = c; return true; }
        acc += tiles;
    }
    return false;
}

// phase 1: g,u GEMM + SiLU -> h. M=64, K=768, NO LDS staging / NO barriers:
// A-fragments load directly from L2-resident xb (16 full 64B lines per load).
__global__ __launch_bounds__(256, 4) void p1_kernel(
    const unsigned short* __restrict__ xb, const unsigned short* __restrict__ w1f,
    const int* __restrict__ counts, const int* __restrict__ perm_t,
    unsigned short* __restrict__ h) {
    __shared__ int s_tok[MT];

    int tid = threadIdx.x;
    int bx, y;
    swz_decode(blockIdx.x, bx, y);
    int e, hbase;
    if (bx < NSHT2) {
        e = 16;
        hbase = HSHARED + bx * MT;
        if (tid < MT) s_tok[tid] = bx * MT + tid;
    } else {
        int t, cnt;
        if (!tile_decode(counts, bx - NSHT2, e, t, cnt)) return;
        hbase = e * ECAP + t * MT;
        if (tid < MT) {
            int slot = t * MT + tid;
            s_tok[tid] = (slot < cnt) ? perm_t[e * ECAP + slot] : 0;
        }
    }
    __syncthreads();

    int lane = tid & 63, wave = tid >> 6;
    int lr = lane & 15, kg8 = (lane >> 4) * 8, jrow = (lane >> 4) * 4;

    const unsigned short* pa0 = xb + (size_t)s_tok[     lr] * DDIM + kg8;
    const unsigned short* pa1 = xb + (size_t)s_tok[16 + lr] * DDIM + kg8;
    const unsigned short* pa2 = xb + (size_t)s_tok[32 + lr] * DDIM + kg8;
    const unsigned short* pa3 = xb + (size_t)s_tok[48 + lr] * DDIM + kg8;

    const unsigned short* pg = w1f + ((((size_t)e * 48 + (y * 8 + wave * 2    )) * 24) * 64 + lane) * 8;
    const unsigned short* pu = w1f + ((((size_t)e * 48 + (y * 8 + wave * 2 + 1)) * 24) * 64 + lane) * 8;

    f32x4 ag0 = (f32x4)0.f, ag1 = (f32x4)0.f, ag2 = (f32x4)0.f, ag3 = (f32x4)0.f;
    f32x4 au0 = (f32x4)0.f, au1 = (f32x4)0.f, au2 = (f32x4)0.f, au3 = (f32x4)0.f;

    #pragma unroll
    for (int ks = 0; ks < 24; ++ks) {
        short8 bg = *(const short8*)(pg + (size_t)ks * 512);
        short8 bu = *(const short8*)(pu + (size_t)ks * 512);
        short8 a0 = *(const short8*)(pa0 + ks * 32);
        short8 a1 = *(const short8*)(pa1 + ks * 32);
        short8 a2 = *(const short8*)(pa2 + ks * 32);
        short8 a3 = *(const short8*)(pa3 + ks * 32);
        ag0 = __builtin_amdgcn_mfma_f32_16x16x32_bf16(a0, bg, ag0, 0, 0, 0);
        au0 = __builtin_amdgcn_mfma_f32_16x16x32_bf16(a0, bu, au0, 0, 0, 0);
        ag1 = __builtin_amdgcn_mfma_f32_16x16x32_bf16(a1, bg, ag1, 0, 0, 0);
        au1 = __builtin_amdgcn_mfma_f32_16x16x32_bf16(a1, bu, au1, 0, 0, 0);
        ag2 = __builtin_amdgcn_mfma_f32_16x16x32_bf16(a2, bg, ag2, 0, 0, 0);
        au2 = __builtin_amdgcn_mfma_f32_16x16x32_bf16(a2, bu, au2, 0, 0, 0);
        ag3 = __builtin_amdgcn_mfma_f32_16x16x32_bf16(a3, bg, ag3, 0, 0, 0);
        au3 = __builtin_amdgcn_mfma_f32_16x16x32_bf16(a3, bu, au3, 0, 0, 0);
    }

    int colg = y * 64 + wave * 16 + lr;
    #pragma unroll
    for (int mf = 0; mf < 4; ++mf) {
        f32x4 g4 = (mf == 0) ? ag0 : (mf == 1) ? ag1 : (mf == 2) ? ag2 : ag3;
        f32x4 u4 = (mf == 0) ? au0 : (mf == 1) ? au1 : (mf == 2) ? au2 : au3;
        #pragma unroll
        for (int j = 0; j < 4; ++j) {
            int tl = mf * 16 + jrow + j;
            float g = g4[j], u = u4[j];
            float hv = g / (1.f + __expf(-g)) * u;
            h[(size_t)(hbase + tl) * IDIM + colg] = f2bf(hv);
        }
    }
}

// phase 2: out GEMM + weighted atomic accumulate. M=64, K=384, direct A loads.
__global__ __launch_bounds__(256, 4) void p2_kernel(
    const unsigned short* __restrict__ h, const unsigned short* __restrict__ wdf,
    const int* __restrict__ counts,
    const int* __restrict__ perm_t, const float* __restrict__ perm_w,
    float* __restrict__ out) {
    __shared__ int   s_tok[MT];
    __shared__ float s_w[MT];

    int tid = threadIdx.x;
    int bx, y;
    swz_decode(blockIdx.x, bx, y);
    int e, hbase;
    if (bx < NSHT2) {
        e = 16;
        hbase = HSHARED + bx * MT;
        if (tid < MT) { s_tok[tid] = bx * MT + tid; s_w[tid] = 1.f; }
    } else {
        int t, cnt;
        if (!tile_decode(counts, bx - NSHT2, e, t, cnt)) return;
        hbase = e * ECAP + t * MT;
        if (tid < MT) {
            int slot = t * MT + tid;
            bool v = slot < cnt;
            s_tok[tid] = v ? perm_t[e * ECAP + slot] : 0;
            s_w[tid]   = v ? perm_w[e * ECAP + slot] : 0.f;
        }
    }
    __syncthreads();

    int lane = tid & 63, wave = tid >> 6;
    int lr = lane & 15, kg8 = (lane >> 4) * 8, jrow = (lane >> 4) * 4;

    const unsigned short* pa0 = h + (size_t)(hbase +      lr) * IDIM + kg8;
    const unsigned short* pa1 = h + (size_t)(hbase + 16 + lr) * IDIM + kg8;
    const unsigned short* pa2 = h + (size_t)(hbase + 32 + lr) * IDIM + kg8;
    const unsigned short* pa3 = h + (size_t)(hbase + 48 + lr) * IDIM + kg8;

    const unsigned short* p0 = wdf + ((((size_t)e * 48 + (y * 8 + wave * 2    )) * 12) * 64 + lane) * 8;
    const unsigned short* p1 = wdf + ((((size_t)e * 48 + (y * 8 + wave * 2 + 1)) * 12) * 64 + lane) * 8;

    f32x4 c00 = (f32x4)0.f, c01 = (f32x4)0.f, c02 = (f32x4)0.f, c03 = (f32x4)0.f;
    f32x4 c10 = (f32x4)0.f, c11 = (f32x4)0.f, c12 = (f32x4)0.f, c13 = (f32x4)0.f;

    #pragma unroll
    for (int ks = 0; ks < 12; ++ks) {
        short8 b0 = *(const short8*)(p0 + (size_t)ks * 512);
        short8 b1 = *(const short8*)(p1 + (size_t)ks * 512);
        short8 a0 = *(const short8*)(pa0 + ks * 32);
        short8 a1 = *(const short8*)(pa1 + ks * 32);
        short8 a2 = *(const short8*)(pa2 + ks * 32);
        short8 a3 = *(const short8*)(pa3 + ks * 32);
        c00 = __builtin_amdgcn_mfma_f32_16x16x32_bf16(a0, b0, c00, 0, 0, 0);
        c10 = __builtin_amdgcn_mfma_f32_16x16x32_bf16(a0, b1, c10, 0, 0, 0);
        c01 = __builtin_amdgcn_mfma_f32_16x16x32_bf16(a1, b0, c01, 0, 0, 0);
        c11 = __builtin_amdgcn_mfma_f32_16x16x32_bf16(a1, b1, c11, 0, 0, 0);
        c02 = __builtin_amdgcn_mfma_f32_16x16x32_bf16(a2, b0, c02, 0, 0, 0);
        c12 = __builtin_amdgcn_mfma_f32_16x16x32_bf16(a2, b1, c12, 0, 0, 0);
        c03 = __builtin_amdgcn_mfma_f32_16x16x32_bf16(a3, b0, c03, 0, 0, 0);
        c13 = __builtin_amdgcn_mfma_f32_16x16x32_bf16(a3, b1, c13, 0, 0, 0);
    }

    int col0 = y * 128 + wave * 32 + lr;
    #pragma unroll
    for (int mf = 0; mf < 4; ++mf) {
        f32x4 v0 = (mf == 0) ? c00 : (mf == 1) ? c01 : (mf == 2) ? c02 : c03;
        f32x4 v1 = (mf == 0) ? c10 : (mf == 1) ? c11 : (mf == 2) ? c12 : c13;
        #pragma unroll
        for (int j = 0; j < 4; ++j) {
            int tl = mf * 16 + jrow + j;
            float w = s_w[tl];
            if (w == 0.f) continue;
            float* orow = out + (size_t)s_tok[tl] * DDIM;
            atomicAdd(orow + col0,      w * v0[j]);
            atomicAdd(orow + col0 + 16, w * v1[j]);
        }
    }
}

extern "C" void kernel_launch(void* const* d_in, const int* in_sizes, int n_in,
                              void* d_out, int out_size, void* d_ws, size_t ws_size,
                              hipStream_t stream) {
    const float* x      = (const float*)d_in[0];
    const float* gate_w = (const float*)d_in[1];
    const float* sg_w   = (const float*)d_in[2];
    const float* su_w   = (const float*)d_in[3];
    const float* sd_w   = (const float*)d_in[4];
    const float* rg_w   = (const float*)d_in[5];
    const float* ru_w   = (const float*)d_in[6];
    const float* rd_w   = (const float*)d_in[7];
    float* out = (float*)d_out;

    char* ws = (char*)d_ws;
    int*   counts    = (int*)(ws + 0);
    int*   perm_t    = (int*)(ws + 1024);
    float* perm_w    = (float*)(ws + 132096);
    float* p_partial = (float*)(ws + 263168);
    int*   topk_i    = (int*)(ws + 295936);
    float* topk_w    = (float*)(ws + 312320);
    unsigned short* xb  = (unsigned short*)(ws + WS_XB);
    unsigned short* w1f = (unsigned short*)(ws + WS_W1F);
    unsigned short* wdf = (unsigned short*)(ws + WS_WDF);
    unsigned short* hbuf= (unsigned short*)(ws + WS_H);

    gate_kernel<<<GBLK, 256, 0, stream>>>(x, gate_w, topk_i, topk_w, p_partial);

    convroute_kernel<<<CR_END, 256, 0, stream>>>(
        x, rg_w, ru_w, sg_w, su_w, rd_w, sd_w,
        (float4*)out, xb, w1f, wdf,
        topk_i, topk_w, p_partial, counts, perm_t, perm_w,
        out + (size_t)NTOK * DDIM);

    p1_kernel<<<NW2, 256, 0, stream>>>(xb, w1f, counts, perm_t, hbuf);

    p2_kernel<<<NW2, 256, 0, stream>>>(hbuf, wdf, counts, perm_t, perm_w, out);
}

// Round 14
// 95.328 us; speedup vs baseline: 1.2803x; 1.2803x over previous
//
#include <hip/hip_runtime.h>
#include <math.h>

#define NTOK 2048
#define DDIM 768
#define IDIM 384
#define NEXP 16
#define ECAP 2048                      // per-expert perm capacity
#define HSHARED (NEXP * ECAP)          // h row offset of shared-expert rows
#define GBLK (NTOK / 4)                // gate blocks = 512

// M=32 tiling (TLP-first)
#define MT 32
#define NSHT3 64                       // shared m-tiles (2048/32)
#define NRT3 144                       // max routed m-tiles (4096/32 + 16)
#define NT3 (NSHT3 + NRT3)             // 208
#define NW3 (NT3 * 6)                  // 1248 = 8 * 156
#define CH3 (NW3 / 8)                  // 156

// convroute grid segmentation: [0] route | zero 384 | x 192 | w1 816 | wd 816
#define CR_Z0 1
#define CR_X0 (CR_Z0 + 384)            // 385
#define CR_W10 (CR_X0 + 192)           // 577
#define CR_WD0 (CR_W10 + 816)          // 1393
#define CR_END (CR_WD0 + 816)          // 2209

typedef __attribute__((ext_vector_type(8))) short short8;   // 8 bf16 = 4 VGPR
typedef __attribute__((ext_vector_type(4))) float f32x4;    // MFMA C/D

__device__ __forceinline__ unsigned short f2bf(float f) {
    unsigned int u = __float_as_uint(f);
    unsigned int r = (u + 0x7fffu + ((u >> 16) & 1u)) >> 16;   // RNE
    return (unsigned short)r;
}

// async global->LDS, 16B/lane: LDS dest = wave-uniform base + lane*16.
__device__ __forceinline__ void gload16(const void* g, void* l) {
    __builtin_amdgcn_global_load_lds(
        (const __attribute__((address_space(1))) void*)g,
        (__attribute__((address_space(3))) void*)l, 16, 0, 0);
}

// ---------------- workspace layout (bytes) ----------------
// 0      counts[16]
// 1024   perm_t[16*2048] int   | 132096 perm_w[16*2048] f32
// 263168 p_partial[512*16] f32 | 295936 topk_i | 312320 topk_w
#define WS_XB   1048576u
#define WS_W1F  4194304u
#define WS_WDF  24248320u
#define WS_H    34275328u

// Standalone gate (own regalloc): shuffle-only softmax/top2. Wave = 1 token.
__global__ __launch_bounds__(256) void gate_kernel(
    const float* __restrict__ x, const float* __restrict__ gate_w,
    int* __restrict__ topk_i, float* __restrict__ topk_w,
    float* __restrict__ p_partial) {
    __shared__ float p_blk[16];
    int tid = threadIdx.x;
    if (tid < 16) p_blk[tid] = 0.f;
    __syncthreads();

    int wave = tid >> 6, lane = tid & 63;
    int n = blockIdx.x * 4 + wave;
    int e = lane >> 2, q = lane & 3;
    const float4* xr = (const float4*)(x + (size_t)n * DDIM);
    const float4* wr = (const float4*)(gate_w + (size_t)e * DDIM);
    float s = 0.f;
    #pragma unroll 4
    for (int k = q * 48; k < q * 48 + 48; ++k) {
        float4 a = xr[k], b = wr[k];
        s += a.x * b.x + a.y * b.y + a.z * b.z + a.w * b.w;
    }
    s += __shfl_xor(s, 1);
    s += __shfl_xor(s, 2);
    float logit = s * 2.5f;

    float m = logit;
    #pragma unroll
    for (int mask = 4; mask < 64; mask <<= 1)
        m = fmaxf(m, __shfl_xor(m, mask));
    float ex = __expf(logit - m);
    float sum = ex;
    #pragma unroll
    for (int mask = 4; mask < 64; mask <<= 1)
        sum += __shfl_xor(sum, mask);
    float sc = ex / sum;

    float v = sc; int idx = e;
    #pragma unroll
    for (int mask = 4; mask < 64; mask <<= 1) {
        float ov = __shfl_xor(v, mask);
        int   oi = __shfl_xor(idx, mask);
        if (ov > v || (ov == v && oi < idx)) { v = ov; idx = oi; }
    }
    float b0 = v; int i0 = idx;
    v = (e == i0) ? -1.f : sc; idx = e;
    #pragma unroll
    for (int mask = 4; mask < 64; mask <<= 1) {
        float ov = __shfl_xor(v, mask);
        int   oi = __shfl_xor(idx, mask);
        if (ov > v || (ov == v && oi < idx)) { v = ov; idx = oi; }
    }
    float b1 = v; int i1 = idx;
    float rs = 1.f / (b0 + b1);

    if (lane == 0) {
        topk_i[n * 2] = i0; topk_i[n * 2 + 1] = i1;
        topk_w[n * 2] = b0 * rs; topk_w[n * 2 + 1] = b1 * rs;
    }
    if (q == 0) atomicAdd(&p_blk[e], sc);   // LDS only
    __syncthreads();
    if (tid < 16) p_partial[blockIdx.x * 16 + tid] = p_blk[tid];
}

// Fused bulk: route(b0) | zero d_out | x conv | w1 conv (LDS transpose) |
// wd conv (LDS transpose). Reads AND writes coalesced.
__global__ __launch_bounds__(256) void convroute_kernel(
    const float* __restrict__ x,
    const float* __restrict__ rgw, const float* __restrict__ ruw,
    const float* __restrict__ sgw, const float* __restrict__ suw,
    const float* __restrict__ rdw, const float* __restrict__ sdw,
    float4* __restrict__ out4,
    unsigned short* __restrict__ xb, unsigned short* __restrict__ w1f,
    unsigned short* __restrict__ wdf,
    const int* __restrict__ topk_i, const float* __restrict__ topk_w,
    const float* __restrict__ p_partial,
    int* __restrict__ counts, int* __restrict__ perm_t, float* __restrict__ perm_w,
    float* __restrict__ out_aux) {
    __shared__ unsigned short sbuf[16 * 780];   // 24,960 B (max of all branches)
    int b = blockIdx.x, tid = threadIdx.x;

    if (b == 0) {                                    // ---- route ----
        float* s_p    = (float*)sbuf;                // 256
        float* s_psum = s_p + 256;                   // 16
        int*   s_cnt  = (int*)(s_psum + 16);         // 16
        int*   s_cur  = s_cnt + 16;                  // 16
        {
            int e = tid & 15, g = tid >> 4;
            float acc = 0.f;
            for (int bb = g; bb < GBLK; bb += 16) acc += p_partial[bb * 16 + e];
            s_p[tid] = acc;
        }
        if (tid < 16) { s_cnt[tid] = 0; s_cur[tid] = 0; }
        __syncthreads();
        if (tid < 16) {
            float a = 0.f;
            #pragma unroll
            for (int g = 0; g < 16; ++g) a += s_p[g * 16 + tid];
            s_psum[tid] = a;
        }
        for (int n = tid; n < NTOK; n += 256) {
            atomicAdd(&s_cnt[topk_i[n * 2]], 1);
            atomicAdd(&s_cnt[topk_i[n * 2 + 1]], 1);
        }
        __syncthreads();
        if (tid < 16) counts[tid] = s_cnt[tid];
        if (tid == 0) {
            float a = 0.f;
            for (int e = 0; e < 16; ++e) a += (float)s_cnt[e] * s_psum[e];
            out_aux[0] = a * 16.f / ((float)NTOK * (float)NTOK);
        }
        for (int n = tid; n < NTOK; n += 256) {
            #pragma unroll
            for (int k = 0; k < 2; ++k) {
                int e = topk_i[n * 2 + k];
                int pos = atomicAdd(&s_cur[e], 1);
                perm_t[e * ECAP + pos] = n;
                perm_w[e * ECAP + pos] = topk_w[n * 2 + k];
            }
        }
        return;
    }

    if (b < CR_X0) {                                 // ---- zero d_out ----
        float4 z = make_float4(0.f, 0.f, 0.f, 0.f);
        float4* dst = out4 + (b - CR_Z0) * 1024 + tid;
        #pragma unroll
        for (int j = 0; j < 4; ++j) dst[j * 256] = z;
        return;
    }

    if (b < CR_W10) {                                // ---- x conv (plain) ----
        int bb = b - CR_X0;
        #pragma unroll
        for (int j = 0; j < 4; ++j) {
            int i = bb * 1024 + j * 256 + tid;
            const float* s = x + (size_t)i * 8;
            float4 v0 = *(const float4*)s, v1 = *(const float4*)(s + 4);
            short8 o;
            o[0]=f2bf(v0.x); o[1]=f2bf(v0.y); o[2]=f2bf(v0.z); o[3]=f2bf(v0.w);
            o[4]=f2bf(v1.x); o[5]=f2bf(v1.y); o[6]=f2bf(v1.z); o[7]=f2bf(v1.w);
            *(short8*)(xb + (size_t)i * 8) = o;
        }
        return;
    }

    if (b < CR_WD0) {                                // ---- w1 conv, LDS transpose ----
        int bb = b - CR_W10;
        int E = bb / 48, rg = bb % 48;
        const float* gsrc_ = (E == 16) ? sgw : rgw + (size_t)E * (IDIM * DDIM);
        const float* usrc_ = (E == 16) ? suw : ruw + (size_t)E * (IDIM * DDIM);
        const float* src = ((rg & 1) ? usrc_ : gsrc_) + (size_t)(rg >> 1) * 16 * DDIM;
        #pragma unroll
        for (int i = 0; i < 12; ++i) {
            int idx = i * 256 + tid;                 // 0..3071 float4
            int r = idx / 192, c4 = idx - r * 192;
            float4 v = ((const float4*)(src + (size_t)r * DDIM))[c4];
            ushort4 o4;
            o4.x = f2bf(v.x); o4.y = f2bf(v.y); o4.z = f2bf(v.z); o4.w = f2bf(v.w);
            *(ushort4*)(sbuf + r * 780 + c4 * 4) = o4;
        }
        __syncthreads();
        unsigned short* wbase = w1f + (size_t)E * (DDIM * DDIM) + (size_t)rg * 24 * 512;
        #pragma unroll
        for (int c = 0; c < 6; ++c) {
            int cc = c * 256 + tid;                  // 0..1535 chunks
            int ks = cc >> 6, l = cc & 63;
            short8 v8 = *(const short8*)(sbuf + (l & 15) * 780 + ks * 32 + (l >> 4) * 8);
            *(short8*)(wbase + (size_t)(ks * 64 + l) * 8) = v8;
        }
        return;
    }

    {                                                // ---- wd conv, LDS transpose ----
        int bb = b - CR_WD0;
        int E = bb / 48, cg = bb % 48;
        const float* src = ((E == 16) ? sdw : rdw + (size_t)E * (DDIM * IDIM))
                         + (size_t)cg * 16 * IDIM;
        #pragma unroll
        for (int i = 0; i < 6; ++i) {
            int idx = i * 256 + tid;                 // 0..1535 float4
            int r = idx / 96, c4 = idx - r * 96;
            float4 v = ((const float4*)(src + (size_t)r * IDIM))[c4];
            ushort4 o4;
            o4.x = f2bf(v.x); o4.y = f2bf(v.y); o4.z = f2bf(v.z); o4.w = f2bf(v.w);
            *(ushort4*)(sbuf + r * 390 + c4 * 4) = o4;
        }
        __syncthreads();
        unsigned short* wbase = wdf + (size_t)E * (DDIM * IDIM) + (size_t)cg * 12 * 512;
        #pragma unroll
        for (int c = 0; c < 3; ++c) {
            int cc = c * 256 + tid;                  // 0..767 chunks
            int ks = cc >> 6, l = cc & 63;
            short8 v8 = *(const short8*)(sbuf + (l & 15) * 390 + ks * 32 + (l >> 4) * 8);
            *(short8*)(wbase + (size_t)(ks * 64 + l) * 8) = v8;
        }
    }
}

// XCD-bijective swizzle over the NW3 flattened (bx, y) space.
__device__ __forceinline__ void swz_decode(int lid, int& bx, int& y) {
    int wid = (lid & 7) * CH3 + (lid >> 3);
    bx = wid / 6;
    y = wid - bx * 6;
}

// routed tile index r -> (expert e, within-expert 32-tile t, count).
__device__ __forceinline__ bool tile_decode(const int* __restrict__ counts,
                                            int r, int& e, int& t, int& cnt) {
    int acc = 0;
    for (int ee = 0; ee < NEXP; ++ee) {
        int c = counts[ee];
        int tiles = (c + 31) >> 5;
        if (r < acc + tiles) { e = ee; t = r - acc; cnt = c; return true; }
        acc += tiles;
    }
    return false;
}

// phase 1: g,u GEMM + SiLU -> h. M=32, K=768 in 2 chunks of 384 (24KB LDS).
// grid NW3 (1248 blocks, ~20 waves/CU): TLP-first.
__global__ __launch_bounds__(256, 6) void p1_kernel(
    const unsigned short* __restrict__ xb, const unsigned short* __restrict__ w1f,
    const int* __restrict__ counts, const int* __restrict__ perm_t,
    unsigned short* __restrict__ h) {
    __shared__ unsigned short xs[24 * 512];   // 24,576 B  [2 mf][12 ksl][512]
    __shared__ int s_tok[MT];

    int tid = threadIdx.x;
    int bx, y;
    swz_decode(blockIdx.x, bx, y);
    int e, hbase;
    if (bx < NSHT3) {
        e = 16;
        hbase = HSHARED + bx * MT;
        if (tid < MT) s_tok[tid] = bx * MT + tid;
    } else {
        int t, cnt;
        if (!tile_decode(counts, bx - NSHT3, e, t, cnt)) return;
        hbase = e * ECAP + t * MT;
        if (tid < MT) {
            int slot = t * MT + tid;
            s_tok[tid] = (slot < cnt) ? perm_t[e * ECAP + slot] : 0;
        }
    }
    __syncthreads();

    int lane = tid & 63, wave = tid >> 6;
    int lr = lane & 15, kg8 = (lane >> 4) * 8, jrow = (lane >> 4) * 4;

    // staging: wave w stages rows r = w*6+c (mf = w>>1, ksl = (w&1)*6+c)
    const unsigned short* gsrc = xb
        + (size_t)s_tok[(wave >> 1) * 16 + lr] * DDIM + kg8;
    int kslbase = (wave & 1) * 6;

    const unsigned short* pg = w1f + ((((size_t)e * 48 + (y * 8 + wave * 2    )) * 24) * 64 + lane) * 8;
    const unsigned short* pu = w1f + ((((size_t)e * 48 + (y * 8 + wave * 2 + 1)) * 24) * 64 + lane) * 8;

    f32x4 ag0 = (f32x4)0.f, ag1 = (f32x4)0.f;
    f32x4 au0 = (f32x4)0.f, au1 = (f32x4)0.f;

    #pragma unroll
    for (int ch = 0; ch < 2; ++ch) {
        if (ch) __syncthreads();
        #pragma unroll
        for (int c = 0; c < 6; ++c)
            gload16(gsrc + (ch * 12 + kslbase + c) * 32,
                    &xs[(wave * 6 + c) * 512]);
        __syncthreads();                         // compiler drains vmcnt first

        #pragma unroll
        for (int ksl = 0; ksl < 12; ++ksl) {
            int ksg = ch * 12 + ksl;
            short8 bg = *(const short8*)(pg + (size_t)ksg * 512);
            short8 bu = *(const short8*)(pu + (size_t)ksg * 512);
            short8 a0 = *(const short8*)(xs + (     ksl) * 512 + lane * 8);
            short8 a1 = *(const short8*)(xs + (12 + ksl) * 512 + lane * 8);
            ag0 = __builtin_amdgcn_mfma_f32_16x16x32_bf16(a0, bg, ag0, 0, 0, 0);
            au0 = __builtin_amdgcn_mfma_f32_16x16x32_bf16(a0, bu, au0, 0, 0, 0);
            ag1 = __builtin_amdgcn_mfma_f32_16x16x32_bf16(a1, bg, ag1, 0, 0, 0);
            au1 = __builtin_amdgcn_mfma_f32_16x16x32_bf16(a1, bu, au1, 0, 0, 0);
        }
    }

    int colg = y * 64 + wave * 16 + lr;
    #pragma unroll
    for (int mf = 0; mf < 2; ++mf) {
        f32x4 g4 = mf ? ag1 : ag0;
        f32x4 u4 = mf ? au1 : au0;
        #pragma unroll
        for (int j = 0; j < 4; ++j) {
            int tl = mf * 16 + jrow + j;
            float g = g4[j], u = u4[j];
            float hv = g / (1.f + __expf(-g)) * u;
            h[(size_t)(hbase + tl) * IDIM + colg] = f2bf(hv);
        }
    }
}

// phase 2: out GEMM + weighted atomic accumulate. M=32, K=384 single chunk.
__global__ __launch_bounds__(256, 6) void p2_kernel(
    const unsigned short* __restrict__ h, const unsigned short* __restrict__ wdf,
    const int* __restrict__ counts,
    const int* __restrict__ perm_t, const float* __restrict__ perm_w,
    float* __restrict__ out) {
    __shared__ unsigned short hs[24 * 512];   // 24,576 B [2 mf][12 ksl][512]
    __shared__ int   s_tok[MT];
    __shared__ float s_w[MT];

    int tid = threadIdx.x;
    int bx, y;
    swz_decode(blockIdx.x, bx, y);
    int e, hbase;
    if (bx < NSHT3) {
        e = 16;
        hbase = HSHARED + bx * MT;
        if (tid < MT) { s_tok[tid] = bx * MT + tid; s_w[tid] = 1.f; }
    } else {
        int t, cnt;
        if (!tile_decode(counts, bx - NSHT3, e, t, cnt)) return;
        hbase = e * ECAP + t * MT;
        if (tid < MT) {
            int slot = t * MT + tid;
            bool v = slot < cnt;
            s_tok[tid] = v ? perm_t[e * ECAP + slot] : 0;
            s_w[tid]   = v ? perm_w[e * ECAP + slot] : 0.f;
        }
    }
    __syncthreads();

    int lane = tid & 63, wave = tid >> 6;
    int lr = lane & 15, kg8 = (lane >> 4) * 8, jrow = (lane >> 4) * 4;

    const unsigned short* gsrc = h
        + (size_t)(hbase + (wave >> 1) * 16 + lr) * IDIM + kg8;
    int kslbase = (wave & 1) * 6;
    #pragma unroll
    for (int c = 0; c < 6; ++c)
        gload16(gsrc + (kslbase + c) * 32, &hs[(wave * 6 + c) * 512]);
    __syncthreads();

    const unsigned short* p0 = wdf + ((((size_t)e * 48 + (y * 8 + wave * 2    )) * 12) * 64 + lane) * 8;
    const unsigned short* p1 = wdf + ((((size_t)e * 48 + (y * 8 + wave * 2 + 1)) * 12) * 64 + lane) * 8;

    f32x4 c00 = (f32x4)0.f, c01 = (f32x4)0.f;
    f32x4 c10 = (f32x4)0.f, c11 = (f32x4)0.f;

    #pragma unroll
    for (int ksl = 0; ksl < 12; ++ksl) {
        short8 b0 = *(const short8*)(p0 + (size_t)ksl * 512);
        short8 b1 = *(const short8*)(p1 + (size_t)ksl * 512);
        short8 a0 = *(const short8*)(hs + (     ksl) * 512 + lane * 8);
        short8 a1 = *(const short8*)(hs + (12 + ksl) * 512 + lane * 8);
        c00 = __builtin_amdgcn_mfma_f32_16x16x32_bf16(a0, b0, c00, 0, 0, 0);
        c10 = __builtin_amdgcn_mfma_f32_16x16x32_bf16(a0, b1, c10, 0, 0, 0);
        c01 = __builtin_amdgcn_mfma_f32_16x16x32_bf16(a1, b0, c01, 0, 0, 0);
        c11 = __builtin_amdgcn_mfma_f32_16x16x32_bf16(a1, b1, c11, 0, 0, 0);
    }

    int col0 = y * 128 + wave * 32 + lr;
    #pragma unroll
    for (int mf = 0; mf < 2; ++mf) {
        f32x4 v0 = mf ? c01 : c00;
        f32x4 v1 = mf ? c11 : c10;
        #pragma unroll
        for (int j = 0; j < 4; ++j) {
            int tl = mf * 16 + jrow + j;
            float w = s_w[tl];
            if (w == 0.f) continue;
            float* orow = out + (size_t)s_tok[tl] * DDIM;
            atomicAdd(orow + col0,      w * v0[j]);
            atomicAdd(orow + col0 + 16, w * v1[j]);
        }
    }
}

extern "C" void kernel_launch(void* const* d_in, const int* in_sizes, int n_in,
                              void* d_out, int out_size, void* d_ws, size_t ws_size,
                              hipStream_t stream) {
    const float* x      = (const float*)d_in[0];
    const float* gate_w = (const float*)d_in[1];
    const float* sg_w   = (const float*)d_in[2];
    const float* su_w   = (const float*)d_in[3];
    const float* sd_w   = (const float*)d_in[4];
    const float* rg_w   = (const float*)d_in[5];
    const float* ru_w   = (const float*)d_in[6];
    const float* rd_w   = (const float*)d_in[7];
    float* out = (float*)d_out;

    char* ws = (char*)d_ws;
    int*   counts    = (int*)(ws + 0);
    int*   perm_t    = (int*)(ws + 1024);
    float* perm_w    = (float*)(ws + 132096);
    float* p_partial = (float*)(ws + 263168);
    int*   topk_i    = (int*)(ws + 295936);
    float* topk_w    = (float*)(ws + 312320);
    unsigned short* xb  = (unsigned short*)(ws + WS_XB);
    unsigned short* w1f = (unsigned short*)(ws + WS_W1F);
    unsigned short* wdf = (unsigned short*)(ws + WS_WDF);
    unsigned short* hbuf= (unsigned short*)(ws + WS_H);

    gate_kernel<<<GBLK, 256, 0, stream>>>(x, gate_w, topk_i, topk_w, p_partial);

    convroute_kernel<<<CR_END, 256, 0, stream>>>(
        x, rg_w, ru_w, sg_w, su_w, rd_w, sd_w,
        (float4*)out, xb, w1f, wdf,
        topk_i, topk_w, p_partial, counts, perm_t, perm_w,
        out + (size_t)NTOK * DDIM);

    p1_kernel<<<NW3, 256, 0, stream>>>(xb, w1f, counts, perm_t, hbuf);

    p2_kernel<<<NW3, 256, 0, stream>>>(hbuf, wdf, counts, perm_t, perm_w, out);
}

// Round 15
// 95.108 us; speedup vs baseline: 1.2833x; 1.0023x over previous
//
#include <hip/hip_runtime.h>
#include <math.h>

#define NTOK 2048
#define DDIM 768
#define IDIM 384
#define NEXP 16
#define ECAP 2048                      // per-expert perm capacity
#define HSHARED (NEXP * ECAP)          // h row offset of shared-expert rows
#define GBLK (NTOK / 4)                // gate blocks = 512

// M=32 tiling (TLP-first)
#define MT 32
#define NSHT3 64                       // shared m-tiles (2048/32)
#define NRT3 144                       // max routed m-tiles (4096/32 + 16)
#define NT3 (NSHT3 + NRT3)             // 208
#define NW3 (NT3 * 6)                  // 1248 = 8 * 156
#define CH3 (NW3 / 8)                  // 156

// convroute grid segmentation: [0] route | zero 384 | x 192 | w1 816 | wd 816
#define CR_Z0 1
#define CR_X0 (CR_Z0 + 384)            // 385
#define CR_W10 (CR_X0 + 192)           // 577
#define CR_WD0 (CR_W10 + 816)          // 1393
#define CR_END (CR_WD0 + 816)          // 2209

typedef __attribute__((ext_vector_type(8))) short short8;   // 8 bf16 = 4 VGPR
typedef __attribute__((ext_vector_type(4))) float f32x4;    // MFMA C/D

__device__ __forceinline__ unsigned short f2bf(float f) {
    unsigned int u = __float_as_uint(f);
    unsigned int r = (u + 0x7fffu + ((u >> 16) & 1u)) >> 16;   // RNE
    return (unsigned short)r;
}

// async global->LDS, 16B/lane: LDS dest = wave-uniform base + lane*16.
__device__ __forceinline__ void gload16(const void* g, void* l) {
    __builtin_amdgcn_global_load_lds(
        (const __attribute__((address_space(1))) void*)g,
        (__attribute__((address_space(3))) void*)l, 16, 0, 0);
}

// ---------------- workspace layout (bytes) ----------------
// 0      counts[16]
// 1024   perm_t[16*2048] int   | 132096 perm_w[16*2048] f32
// 263168 p_partial[512*16] f32 | 295936 topk_i | 312320 topk_w
#define WS_XB   1048576u
#define WS_W1F  4194304u
#define WS_WDF  24248320u
#define WS_H    34275328u

// Standalone gate (own regalloc): shuffle-only softmax/top2. Wave = 1 token.
__global__ __launch_bounds__(256) void gate_kernel(
    const float* __restrict__ x, const float* __restrict__ gate_w,
    int* __restrict__ topk_i, float* __restrict__ topk_w,
    float* __restrict__ p_partial) {
    __shared__ float p_blk[16];
    int tid = threadIdx.x;
    if (tid < 16) p_blk[tid] = 0.f;
    __syncthreads();

    int wave = tid >> 6, lane = tid & 63;
    int n = blockIdx.x * 4 + wave;
    int e = lane >> 2, q = lane & 3;
    const float4* xr = (const float4*)(x + (size_t)n * DDIM);
    const float4* wr = (const float4*)(gate_w + (size_t)e * DDIM);
    float s = 0.f;
    #pragma unroll 4
    for (int k = q * 48; k < q * 48 + 48; ++k) {
        float4 a = xr[k], b = wr[k];
        s += a.x * b.x + a.y * b.y + a.z * b.z + a.w * b.w;
    }
    s += __shfl_xor(s, 1);
    s += __shfl_xor(s, 2);
    float logit = s * 2.5f;

    float m = logit;
    #pragma unroll
    for (int mask = 4; mask < 64; mask <<= 1)
        m = fmaxf(m, __shfl_xor(m, mask));
    float ex = __expf(logit - m);
    float sum = ex;
    #pragma unroll
    for (int mask = 4; mask < 64; mask <<= 1)
        sum += __shfl_xor(sum, mask);
    float sc = ex / sum;

    float v = sc; int idx = e;
    #pragma unroll
    for (int mask = 4; mask < 64; mask <<= 1) {
        float ov = __shfl_xor(v, mask);
        int   oi = __shfl_xor(idx, mask);
        if (ov > v || (ov == v && oi < idx)) { v = ov; idx = oi; }
    }
    float b0 = v; int i0 = idx;
    v = (e == i0) ? -1.f : sc; idx = e;
    #pragma unroll
    for (int mask = 4; mask < 64; mask <<= 1) {
        float ov = __shfl_xor(v, mask);
        int   oi = __shfl_xor(idx, mask);
        if (ov > v || (ov == v && oi < idx)) { v = ov; idx = oi; }
    }
    float b1 = v; int i1 = idx;
    float rs = 1.f / (b0 + b1);

    if (lane == 0) {
        topk_i[n * 2] = i0; topk_i[n * 2 + 1] = i1;
        topk_w[n * 2] = b0 * rs; topk_w[n * 2 + 1] = b1 * rs;
    }
    if (q == 0) atomicAdd(&p_blk[e], sc);   // LDS only
    __syncthreads();
    if (tid < 16) p_partial[blockIdx.x * 16 + tid] = p_blk[tid];
}

// Fused bulk: route(b0) | zero d_out | x conv | w1 conv (LDS transpose) |
// wd conv (LDS transpose). Reads AND writes coalesced.
__global__ __launch_bounds__(256) void convroute_kernel(
    const float* __restrict__ x,
    const float* __restrict__ rgw, const float* __restrict__ ruw,
    const float* __restrict__ sgw, const float* __restrict__ suw,
    const float* __restrict__ rdw, const float* __restrict__ sdw,
    float4* __restrict__ out4,
    unsigned short* __restrict__ xb, unsigned short* __restrict__ w1f,
    unsigned short* __restrict__ wdf,
    const int* __restrict__ topk_i, const float* __restrict__ topk_w,
    const float* __restrict__ p_partial,
    int* __restrict__ counts, int* __restrict__ perm_t, float* __restrict__ perm_w,
    float* __restrict__ out_aux) {
    __shared__ unsigned short sbuf[16 * 780];   // 24,960 B (max of all branches)
    int b = blockIdx.x, tid = threadIdx.x;

    if (b == 0) {                                    // ---- route ----
        float* s_p    = (float*)sbuf;                // 256
        float* s_psum = s_p + 256;                   // 16
        int*   s_cnt  = (int*)(s_psum + 16);         // 16
        int*   s_cur  = s_cnt + 16;                  // 16
        {
            int e = tid & 15, g = tid >> 4;
            float acc = 0.f;
            for (int bb = g; bb < GBLK; bb += 16) acc += p_partial[bb * 16 + e];
            s_p[tid] = acc;
        }
        if (tid < 16) { s_cnt[tid] = 0; s_cur[tid] = 0; }
        __syncthreads();
        if (tid < 16) {
            float a = 0.f;
            #pragma unroll
            for (int g = 0; g < 16; ++g) a += s_p[g * 16 + tid];
            s_psum[tid] = a;
        }
        for (int n = tid; n < NTOK; n += 256) {
            atomicAdd(&s_cnt[topk_i[n * 2]], 1);
            atomicAdd(&s_cnt[topk_i[n * 2 + 1]], 1);
        }
        __syncthreads();
        if (tid < 16) counts[tid] = s_cnt[tid];
        if (tid == 0) {
            float a = 0.f;
            for (int e = 0; e < 16; ++e) a += (float)s_cnt[e] * s_psum[e];
            out_aux[0] = a * 16.f / ((float)NTOK * (float)NTOK);
        }
        for (int n = tid; n < NTOK; n += 256) {
            #pragma unroll
            for (int k = 0; k < 2; ++k) {
                int e = topk_i[n * 2 + k];
                int pos = atomicAdd(&s_cur[e], 1);
                perm_t[e * ECAP + pos] = n;
                perm_w[e * ECAP + pos] = topk_w[n * 2 + k];
            }
        }
        return;
    }

    if (b < CR_X0) {                                 // ---- zero d_out ----
        float4 z = make_float4(0.f, 0.f, 0.f, 0.f);
        float4* dst = out4 + (b - CR_Z0) * 1024 + tid;
        #pragma unroll
        for (int j = 0; j < 4; ++j) dst[j * 256] = z;
        return;
    }

    if (b < CR_W10) {                                // ---- x conv (plain) ----
        int bb = b - CR_X0;
        #pragma unroll
        for (int j = 0; j < 4; ++j) {
            int i = bb * 1024 + j * 256 + tid;
            const float* s = x + (size_t)i * 8;
            float4 v0 = *(const float4*)s, v1 = *(const float4*)(s + 4);
            short8 o;
            o[0]=f2bf(v0.x); o[1]=f2bf(v0.y); o[2]=f2bf(v0.z); o[3]=f2bf(v0.w);
            o[4]=f2bf(v1.x); o[5]=f2bf(v1.y); o[6]=f2bf(v1.z); o[7]=f2bf(v1.w);
            *(short8*)(xb + (size_t)i * 8) = o;
        }
        return;
    }

    if (b < CR_WD0) {                                // ---- w1 conv, LDS transpose ----
        int bb = b - CR_W10;
        int E = bb / 48, rg = bb % 48;
        const float* gsrc_ = (E == 16) ? sgw : rgw + (size_t)E * (IDIM * DDIM);
        const float* usrc_ = (E == 16) ? suw : ruw + (size_t)E * (IDIM * DDIM);
        const float* src = ((rg & 1) ? usrc_ : gsrc_) + (size_t)(rg >> 1) * 16 * DDIM;
        #pragma unroll
        for (int i = 0; i < 12; ++i) {
            int idx = i * 256 + tid;                 // 0..3071 float4
            int r = idx / 192, c4 = idx - r * 192;
            float4 v = ((const float4*)(src + (size_t)r * DDIM))[c4];
            ushort4 o4;
            o4.x = f2bf(v.x); o4.y = f2bf(v.y); o4.z = f2bf(v.z); o4.w = f2bf(v.w);
            *(ushort4*)(sbuf + r * 780 + c4 * 4) = o4;
        }
        __syncthreads();
        unsigned short* wbase = w1f + (size_t)E * (DDIM * DDIM) + (size_t)rg * 24 * 512;
        #pragma unroll
        for (int c = 0; c < 6; ++c) {
            int cc = c * 256 + tid;                  // 0..1535 chunks
            int ks = cc >> 6, l = cc & 63;
            short8 v8 = *(const short8*)(sbuf + (l & 15) * 780 + ks * 32 + (l >> 4) * 8);
            *(short8*)(wbase + (size_t)(ks * 64 + l) * 8) = v8;
        }
        return;
    }

    {                                                // ---- wd conv, LDS transpose ----
        int bb = b - CR_WD0;
        int E = bb / 48, cg = bb % 48;
        const float* src = ((E == 16) ? sdw : rdw + (size_t)E * (DDIM * IDIM))
                         + (size_t)cg * 16 * IDIM;
        #pragma unroll
        for (int i = 0; i < 6; ++i) {
            int idx = i * 256 + tid;                 // 0..1535 float4
            int r = idx / 96, c4 = idx - r * 96;
            float4 v = ((const float4*)(src + (size_t)r * IDIM))[c4];
            ushort4 o4;
            o4.x = f2bf(v.x); o4.y = f2bf(v.y); o4.z = f2bf(v.z); o4.w = f2bf(v.w);
            *(ushort4*)(sbuf + r * 390 + c4 * 4) = o4;
        }
        __syncthreads();
        unsigned short* wbase = wdf + (size_t)E * (DDIM * IDIM) + (size_t)cg * 12 * 512;
        #pragma unroll
        for (int c = 0; c < 3; ++c) {
            int cc = c * 256 + tid;                  // 0..767 chunks
            int ks = cc >> 6, l = cc & 63;
            short8 v8 = *(const short8*)(sbuf + (l & 15) * 390 + ks * 32 + (l >> 4) * 8);
            *(short8*)(wbase + (size_t)(ks * 64 + l) * 8) = v8;
        }
    }
}

// XCD-bijective swizzle over the NW3 flattened (bx, y) space.
__device__ __forceinline__ void swz_decode(int lid, int& bx, int& y) {
    int wid = (lid & 7) * CH3 + (lid >> 3);
    bx = wid / 6;
    y = wid - bx * 6;
}

// routed tile index r -> (expert e, within-expert 32-tile t, count).
__device__ __forceinline__ bool tile_decode(const int* __restrict__ counts,
                                            int r, int& e, int& t, int& cnt) {
    int acc = 0;
    for (int ee = 0; ee < NEXP; ++ee) {
        int c = counts[ee];
        int tiles = (c + 31) >> 5;
        if (r < acc + tiles) { e = ee; t = r - acc; cnt = c; return true; }
        acc += tiles;
    }
    return false;
}

// phase 1: g,u GEMM + SiLU -> h. M=32, K=768 in 2 chunks of 384 (24KB LDS).
// Epilogue: result staged through LDS -> coalesced 16B/thread h writes.
__global__ __launch_bounds__(256, 6) void p1_kernel(
    const unsigned short* __restrict__ xb, const unsigned short* __restrict__ w1f,
    const int* __restrict__ counts, const int* __restrict__ perm_t,
    unsigned short* __restrict__ h) {
    __shared__ unsigned short xs[24 * 512];   // 24,576 B  [2 mf][12 ksl][512]
    __shared__ int s_tok[MT];

    int tid = threadIdx.x;
    int bx, y;
    swz_decode(blockIdx.x, bx, y);
    int e, hbase;
    if (bx < NSHT3) {
        e = 16;
        hbase = HSHARED + bx * MT;
        if (tid < MT) s_tok[tid] = bx * MT + tid;
    } else {
        int t, cnt;
        if (!tile_decode(counts, bx - NSHT3, e, t, cnt)) return;
        hbase = e * ECAP + t * MT;
        if (tid < MT) {
            int slot = t * MT + tid;
            s_tok[tid] = (slot < cnt) ? perm_t[e * ECAP + slot] : 0;
        }
    }
    __syncthreads();

    int lane = tid & 63, wave = tid >> 6;
    int lr = lane & 15, kg8 = (lane >> 4) * 8, jrow = (lane >> 4) * 4;

    // staging: wave w stages rows r = w*6+c (mf = w>>1, ksl = (w&1)*6+c)
    const unsigned short* gsrc = xb
        + (size_t)s_tok[(wave >> 1) * 16 + lr] * DDIM + kg8;
    int kslbase = (wave & 1) * 6;

    const unsigned short* pg = w1f + ((((size_t)e * 48 + (y * 8 + wave * 2    )) * 24) * 64 + lane) * 8;
    const unsigned short* pu = w1f + ((((size_t)e * 48 + (y * 8 + wave * 2 + 1)) * 24) * 64 + lane) * 8;

    f32x4 ag0 = (f32x4)0.f, ag1 = (f32x4)0.f;
    f32x4 au0 = (f32x4)0.f, au1 = (f32x4)0.f;

    #pragma unroll
    for (int ch = 0; ch < 2; ++ch) {
        if (ch) __syncthreads();
        #pragma unroll
        for (int c = 0; c < 6; ++c)
            gload16(gsrc + (ch * 12 + kslbase + c) * 32,
                    &xs[(wave * 6 + c) * 512]);
        __syncthreads();                         // compiler drains vmcnt first

        #pragma unroll
        for (int ksl = 0; ksl < 12; ++ksl) {
            int ksg = ch * 12 + ksl;
            short8 bg = *(const short8*)(pg + (size_t)ksg * 512);
            short8 bu = *(const short8*)(pu + (size_t)ksg * 512);
            short8 a0 = *(const short8*)(xs + (     ksl) * 512 + lane * 8);
            short8 a1 = *(const short8*)(xs + (12 + ksl) * 512 + lane * 8);
            ag0 = __builtin_amdgcn_mfma_f32_16x16x32_bf16(a0, bg, ag0, 0, 0, 0);
            au0 = __builtin_amdgcn_mfma_f32_16x16x32_bf16(a0, bu, au0, 0, 0, 0);
            ag1 = __builtin_amdgcn_mfma_f32_16x16x32_bf16(a1, bg, ag1, 0, 0, 0);
            au1 = __builtin_amdgcn_mfma_f32_16x16x32_bf16(a1, bu, au1, 0, 0, 0);
        }
    }

    // epilogue: SiLU -> LDS [32 tok][64 col] -> coalesced 16B stores
    __syncthreads();                             // all MFMA LDS reads done
    #pragma unroll
    for (int mf = 0; mf < 2; ++mf) {
        f32x4 g4 = mf ? ag1 : ag0;
        f32x4 u4 = mf ? au1 : au0;
        #pragma unroll
        for (int j = 0; j < 4; ++j) {
            int tl = mf * 16 + jrow + j;
            float g = g4[j], u = u4[j];
            float hv = g / (1.f + __expf(-g)) * u;
            xs[tl * 64 + wave * 16 + lr] = f2bf(hv);
        }
    }
    __syncthreads();
    {
        int row = tid >> 3, off = (tid & 7) * 8;   // 32 rows x 64 shorts
        *(short8*)(h + (size_t)(hbase + row) * IDIM + y * 64 + off) =
            *(const short8*)(xs + row * 64 + off);
    }
}

// phase 2: out GEMM + weighted atomic accumulate. M=32, K=384 single chunk.
__global__ __launch_bounds__(256, 6) void p2_kernel(
    const unsigned short* __restrict__ h, const unsigned short* __restrict__ wdf,
    const int* __restrict__ counts,
    const int* __restrict__ perm_t, const float* __restrict__ perm_w,
    float* __restrict__ out) {
    __shared__ unsigned short hs[24 * 512];   // 24,576 B [2 mf][12 ksl][512]
    __shared__ int   s_tok[MT];
    __shared__ float s_w[MT];

    int tid = threadIdx.x;
    int bx, y;
    swz_decode(blockIdx.x, bx, y);
    int e, hbase;
    if (bx < NSHT3) {
        e = 16;
        hbase = HSHARED + bx * MT;
        if (tid < MT) { s_tok[tid] = bx * MT + tid; s_w[tid] = 1.f; }
    } else {
        int t, cnt;
        if (!tile_decode(counts, bx - NSHT3, e, t, cnt)) return;
        hbase = e * ECAP + t * MT;
        if (tid < MT) {
            int slot = t * MT + tid;
            bool v = slot < cnt;
            s_tok[tid] = v ? perm_t[e * ECAP + slot] : 0;
            s_w[tid]   = v ? perm_w[e * ECAP + slot] : 0.f;
        }
    }
    __syncthreads();

    int lane = tid & 63, wave = tid >> 6;
    int lr = lane & 15, kg8 = (lane >> 4) * 8, jrow = (lane >> 4) * 4;

    const unsigned short* gsrc = h
        + (size_t)(hbase + (wave >> 1) * 16 + lr) * IDIM + kg8;
    int kslbase = (wave & 1) * 6;
    #pragma unroll
    for (int c = 0; c < 6; ++c)
        gload16(gsrc + (kslbase + c) * 32, &hs[(wave * 6 + c) * 512]);
    __syncthreads();

    const unsigned short* p0 = wdf + ((((size_t)e * 48 + (y * 8 + wave * 2    )) * 12) * 64 + lane) * 8;
    const unsigned short* p1 = wdf + ((((size_t)e * 48 + (y * 8 + wave * 2 + 1)) * 12) * 64 + lane) * 8;

    f32x4 c00 = (f32x4)0.f, c01 = (f32x4)0.f;
    f32x4 c10 = (f32x4)0.f, c11 = (f32x4)0.f;

    #pragma unroll
    for (int ksl = 0; ksl < 12; ++ksl) {
        short8 b0 = *(const short8*)(p0 + (size_t)ksl * 512);
        short8 b1 = *(const short8*)(p1 + (size_t)ksl * 512);
        short8 a0 = *(const short8*)(hs + (     ksl) * 512 + lane * 8);
        short8 a1 = *(const short8*)(hs + (12 + ksl) * 512 + lane * 8);
        c00 = __builtin_amdgcn_mfma_f32_16x16x32_bf16(a0, b0, c00, 0, 0, 0);
        c10 = __builtin_amdgcn_mfma_f32_16x16x32_bf16(a0, b1, c10, 0, 0, 0);
        c01 = __builtin_amdgcn_mfma_f32_16x16x32_bf16(a1, b0, c01, 0, 0, 0);
        c11 = __builtin_amdgcn_mfma_f32_16x16x32_bf16(a1, b1, c11, 0, 0, 0);
    }

    int col0 = y * 128 + wave * 32 + lr;
    #pragma unroll
    for (int mf = 0; mf < 2; ++mf) {
        f32x4 v0 = mf ? c01 : c00;
        f32x4 v1 = mf ? c11 : c10;
        #pragma unroll
        for (int j = 0; j < 4; ++j) {
            int tl = mf * 16 + jrow + j;
            float w = s_w[tl];
            if (w == 0.f) continue;
            float* orow = out + (size_t)s_tok[tl] * DDIM;
            atomicAdd(orow + col0,      w * v0[j]);
            atomicAdd(orow + col0 + 16, w * v1[j]);
        }
    }
}

extern "C" void kernel_launch(void* const* d_in, const int* in_sizes, int n_in,
                              void* d_out, int out_size, void* d_ws, size_t ws_size,
                              hipStream_t stream) {
    const float* x      = (const float*)d_in[0];
    const float* gate_w = (const float*)d_in[1];
    const float* sg_w   = (const float*)d_in[2];
    const float* su_w   = (const float*)d_in[3];
    const float* sd_w   = (const float*)d_in[4];
    const float* rg_w   = (const float*)d_in[5];
    const float* ru_w   = (const float*)d_in[6];
    const float* rd_w   = (const float*)d_in[7];
    float* out = (float*)d_out;

    char* ws = (char*)d_ws;
    int*   counts    = (int*)(ws + 0);
    int*   perm_t    = (int*)(ws + 1024);
    float* perm_w    = (float*)(ws + 132096);
    float* p_partial = (float*)(ws + 263168);
    int*   topk_i    = (int*)(ws + 295936);
    float* topk_w    = (float*)(ws + 312320);
    unsigned short* xb  = (unsigned short*)(ws + WS_XB);
    unsigned short* w1f = (unsigned short*)(ws + WS_W1F);
    unsigned short* wdf = (unsigned short*)(ws + WS_WDF);
    unsigned short* hbuf= (unsigned short*)(ws + WS_H);

    gate_kernel<<<GBLK, 256, 0, stream>>>(x, gate_w, topk_i, topk_w, p_partial);

    convroute_kernel<<<CR_END, 256, 0, stream>>>(
        x, rg_w, ru_w, sg_w, su_w, rd_w, sd_w,
        (float4*)out, xb, w1f, wdf,
        topk_i, topk_w, p_partial, counts, perm_t, perm_w,
        out + (size_t)NTOK * DDIM);

    p1_kernel<<<NW3, 256, 0, stream>>>(xb, w1f, counts, perm_t, hbuf);

    p2_kernel<<<NW3, 256, 0, stream>>>(hbuf, wdf, counts, perm_t, perm_w, out);
}